// Round 6
// baseline (534.839 us; speedup 1.0000x reference)
//
#include <hip/hip_runtime.h>

#define RES 256
#define NV 6890
#define CAP 16                         // max verts per 8^3 cell (mean 0.41)
#define NCELL (32*32*32)
#define SEM_ELEMS (RES*RES*RES*3)
#define MAXREC (36*CAP)                // 3*3*4 cells * CAP

typedef float f32x4 __attribute__((ext_vector_type(4)));

// ---------------------------------------------------------------------------
// Kernel 1: zero the per-cell counters (d_ws is re-poisoned before every call).
// ---------------------------------------------------------------------------
__global__ void svox_zero_counts(int* __restrict__ counts) {
    int i = blockIdx.x * blockDim.x + threadIdx.x;
    if (i < NCELL) counts[i] = 0;
}

// ---------------------------------------------------------------------------
// Kernel 2: bucket vertices into 8^3-voxel cells, packed record:
//   rec0 = (vx, vy, vz, bitcast((cx+8)<<20 | (cy+8)<<10 | (cz+8)))
//   rec1 = (c0, c1, c2, 0)
// Biased centers clamped to [0,1023] can never pass the |dv|<=3 window test,
// so edge clamping is value-exact.
// ---------------------------------------------------------------------------
__global__ void svox_bucket(const float* __restrict__ verts,
                            const float* __restrict__ codes,
                            int* __restrict__ counts,
                            f32x4* __restrict__ lists) {
    int n = blockIdx.x * blockDim.x + threadIdx.x;
    if (n >= NV) return;
    float vx = verts[3 * n + 0], vy = verts[3 * n + 1], vz = verts[3 * n + 2];
    int cx = (int)floorf((vx + 0.5f) * 256.0f);
    int cy = (int)floorf((vy + 0.5f) * 256.0f);
    int cz = (int)floorf((vz + 0.5f) * 256.0f);
    int px = min(max(cx + 8, 0), 1023);
    int py = min(max(cy + 8, 0), 1023);
    int pz = min(max(cz + 8, 0), 1023);
    int bx = min(max(cx >> 3, 0), 31);
    int by = min(max(cy >> 3, 0), 31);
    int bz = min(max(cz >> 3, 0), 31);
    int cell = (bx << 10) | (by << 5) | bz;
    int slot = atomicAdd(&counts[cell], 1);
    if (slot < CAP) {
        int pk = (px << 20) | (py << 10) | pz;
        f32x4 r0 = {vx, vy, vz, __int_as_float(pk)};
        f32x4 r1 = {codes[3 * n + 0], codes[3 * n + 1], codes[3 * n + 2], 0.0f};
        lists[(cell * CAP + slot) * 2 + 0] = r0;
        lists[(cell * CAP + slot) * 2 + 1] = r1;
    }
}

// ---------------------------------------------------------------------------
// Kernel 3: gather. One 256-thread block per 8x8x16 voxel tile; candidates
// for the whole tile (3x3x4 cells) staged once into LDS; uniform inner loop.
// Each thread owns one z-quad. Writes every output element exactly once.
// ---------------------------------------------------------------------------
__global__ void __launch_bounds__(256)
svox_gather(const float* __restrict__ occ,
            const int* __restrict__ counts,
            const f32x4* __restrict__ lists,
            f32x4* __restrict__ sem4,
            f32x4* __restrict__ wsum4) {
    __shared__ f32x4 srec[MAXREC * 2];
    __shared__ int s_n;

    const int tid = threadIdx.x;
    const int X = blockIdx.z;          // 0..31  (cell x == X)
    const int Y = blockIdx.y;          // 0..31  (cell y == Y)
    const int Z = blockIdx.x;          // 0..15  (z cells 2Z..2Z+1)

    if (tid == 0) s_n = 0;
    __syncthreads();

    // ---- stage candidate records: cells (X-1..X+1, Y-1..Y+1, 2Z-1..2Z+2) ----
    if (tid < 36) {
        int ox = tid / 12 - 1;               // -1..1
        int oy = (tid / 4) % 3 - 1;          // -1..1
        int oz = tid % 4 - 1;                // -1..2
        int cx = X + ox, cy = Y + oy, cz = 2 * Z + oz;
        if (cx >= 0 && cx < 32 && cy >= 0 && cy < 32 && cz >= 0 && cz < 32) {
            int cell = (cx << 10) | (cy << 5) | cz;
            int cnt = min(counts[cell], CAP);
            if (cnt > 0) {
                int base = atomicAdd(&s_n, cnt);
                int gb = cell * CAP;
                for (int j = 0; j < cnt; ++j) {
                    srec[(base + j) * 2 + 0] = lists[(gb + j) * 2 + 0];
                    srec[(base + j) * 2 + 1] = lists[(gb + j) * 2 + 1];
                }
            }
        }
    }
    __syncthreads();
    const int n = s_n;                       // wave-uniform

    // ---- this thread's z-quad ----
    int x  = (X << 3) + (tid >> 5);          // tid/32: 0..7
    int y  = (Y << 3) + ((tid >> 2) & 7);
    int z0 = (Z << 4) + ((tid & 3) << 2);
    int lin0 = ((x << 8) + y << 8) + z0;     // ((x*256)+y)*256+z0

    float acc[4][4];
#pragma unroll
    for (int q = 0; q < 4; ++q) {
        acc[q][0] = 0.f; acc[q][1] = 0.f; acc[q][2] = 0.f; acc[q][3] = 0.f;
    }

    if (n > 0) {
        const float inv = 1.0f / 256.0f;
        float fx  = ((float)x  + 0.5f) * inv - 0.5f;
        float fy  = ((float)y  + 0.5f) * inv - 0.5f;
        float fz0 = ((float)z0 + 0.5f) * inv - 0.5f;

        const f32x4 o4 = __builtin_nontemporal_load((const f32x4*)&occ[lin0]);
        float occv[4] = {o4.x, o4.y, o4.z, o4.w};

        for (int j = 0; j < n; ++j) {
            f32x4 r0 = srec[j * 2 + 0];      // broadcast LDS read
            int pk = __float_as_int(r0.w);
            int cxb = (pk >> 20) & 1023;     // cx + 8
            int cyb = (pk >> 10) & 1023;
            int czb =  pk        & 1023;
            unsigned dxi = (unsigned)(x  + 8 - cxb + 3);
            unsigned dyi = (unsigned)(y  + 8 - cyb + 3);
            unsigned dzq = (unsigned)(z0 + 8 - czb + 6);
            if (dxi > 6u || dyi > 6u || dzq > 9u) continue;

            f32x4 r1 = srec[j * 2 + 1];
            float dx = fx - r0.x, dy = fy - r0.y;
            float exy = __expf(-8192.0f * (dx * dx + dy * dy));
            int czr = czb - 8;
#pragma unroll
            for (int q = 0; q < 4; ++q) {
                unsigned dzi = (unsigned)(z0 + q - czr + 3);
                if (dzi > 6u) continue;
                if (occv[q] <= 0.0f) continue;
                float dz = fz0 + (float)q * inv - r0.z;
                float w = exy * __expf(-8192.0f * dz * dz);
                acc[q][0] += w * r1.x;
                acc[q][1] += w * r1.y;
                acc[q][2] += w * r1.z;
                acc[q][3] += w;
            }
        }
    }

    int t = lin0 >> 2;
    f32x4 s0 = {acc[0][0], acc[0][1], acc[0][2], acc[1][0]};
    f32x4 s1 = {acc[1][1], acc[1][2], acc[2][0], acc[2][1]};
    f32x4 s2 = {acc[2][2], acc[3][0], acc[3][1], acc[3][2]};
    f32x4 sw = {0.001f + acc[0][3], 0.001f + acc[1][3],
                0.001f + acc[2][3], 0.001f + acc[3][3]};
    __builtin_nontemporal_store(s0, &sem4[t * 3 + 0]);
    __builtin_nontemporal_store(s1, &sem4[t * 3 + 1]);
    __builtin_nontemporal_store(s2, &sem4[t * 3 + 2]);
    __builtin_nontemporal_store(sw, &wsum4[t]);
}

extern "C" void kernel_launch(void* const* d_in, const int* in_sizes, int n_in,
                              void* d_out, int out_size, void* d_ws, size_t ws_size,
                              hipStream_t stream) {
    const float* verts = (const float*)d_in[0];   // (6890,3) f32
    const float* codes = (const float*)d_in[1];   // (6890,3) f32
    const float* occ   = (const float*)d_in[2];   // (256,256,256) f32
    // d_in[3] = smpl_faces (unused by the reference computation)

    f32x4* sem4  = (f32x4*)d_out;                       // 12,582,912 f32x4
    f32x4* wsum4 = (f32x4*)((float*)d_out + SEM_ELEMS); // 4,194,304 f32x4

    int*   counts = (int*)d_ws;                   // 32768 ints
    f32x4* lists  = (f32x4*)(counts + NCELL);     // 32768*CAP*2 f32x4 = 16 MB

    svox_zero_counts<<<(NCELL + 255) / 256, 256, 0, stream>>>(counts);
    svox_bucket<<<(NV + 255) / 256, 256, 0, stream>>>(verts, codes, counts, lists);
    dim3 grid(16, 32, 32);                        // (Z, Y, X)
    svox_gather<<<grid, 256, 0, stream>>>(occ, counts, lists, sem4, wsum4);
}

// Round 7
// 389.364 us; speedup vs baseline: 1.3736x; 1.3736x over previous
//
#include <hip/hip_runtime.h>

#define RES 256
#define NV 6890
#define CAP 16                         // max verts per 8^3 cell (mean 0.41)
#define NCELL (32*32*32)
#define SEM_ELEMS (RES*RES*RES*3)

typedef float f32x4 __attribute__((ext_vector_type(4)));

// ---------------------------------------------------------------------------
// Kernel 1: zero the per-cell counters (d_ws is re-poisoned before every call).
// ---------------------------------------------------------------------------
__global__ void svox_zero_counts(int* __restrict__ counts) {
    int i = blockIdx.x * blockDim.x + threadIdx.x;
    if (i < NCELL) counts[i] = 0;
}

// ---------------------------------------------------------------------------
// Kernel 2: bucket vertices into 8^3-voxel cells, packed record:
//   rec0 = (vx, vy, vz, bitcast((cx+8)<<20 | (cy+8)<<10 | (cz+8)))
//   rec1 = (c0, c1, c2, 0)
// Biased centers clamped to [0,1023] can never pass the |dv|<=3 window test,
// so edge clamping is value-exact.
// ---------------------------------------------------------------------------
__global__ void svox_bucket(const float* __restrict__ verts,
                            const float* __restrict__ codes,
                            int* __restrict__ counts,
                            f32x4* __restrict__ lists) {
    int n = blockIdx.x * blockDim.x + threadIdx.x;
    if (n >= NV) return;
    float vx = verts[3 * n + 0], vy = verts[3 * n + 1], vz = verts[3 * n + 2];
    int cx = (int)floorf((vx + 0.5f) * 256.0f);
    int cy = (int)floorf((vy + 0.5f) * 256.0f);
    int cz = (int)floorf((vz + 0.5f) * 256.0f);
    int px = min(max(cx + 8, 0), 1023);
    int py = min(max(cy + 8, 0), 1023);
    int pz = min(max(cz + 8, 0), 1023);
    int bx = min(max(cx >> 3, 0), 31);
    int by = min(max(cy >> 3, 0), 31);
    int bz = min(max(cz >> 3, 0), 31);
    int cell = (bx << 10) | (by << 5) | bz;
    int slot = atomicAdd(&counts[cell], 1);
    if (slot < CAP) {
        int pk = (px << 20) | (py << 10) | pz;
        f32x4 r0 = {vx, vy, vz, __int_as_float(pk)};
        f32x4 r1 = {codes[3 * n + 0], codes[3 * n + 1], codes[3 * n + 2], 0.0f};
        lists[(cell * CAP + slot) * 2 + 0] = r0;
        lists[(cell * CAP + slot) * 2 + 1] = r1;
    }
}

// ---------------------------------------------------------------------------
// Kernel 3: per-cell neighborhood-nonempty byte mask (27-neighborhood OR).
// A gather thread's 8 candidate cells always lie in its own cell's +-1
// neighborhood, so nbr==0 proves the thread has zero candidates.
// ---------------------------------------------------------------------------
__global__ void svox_nbrmask(const int* __restrict__ counts,
                             unsigned char* __restrict__ nbr) {
    int i = blockIdx.x * blockDim.x + threadIdx.x;
    if (i >= NCELL) return;
    int bz = i & 31, by = (i >> 5) & 31, bx = i >> 10;
    int total = 0;
    for (int dx = -1; dx <= 1; ++dx) {
        int cx = bx + dx; if ((unsigned)cx >= 32u) continue;
        for (int dy = -1; dy <= 1; ++dy) {
            int cy = by + dy; if ((unsigned)cy >= 32u) continue;
            for (int dz = -1; dz <= 1; ++dz) {
                int cz = bz + dz; if ((unsigned)cz >= 32u) continue;
                total += counts[(cx << 10) | (cy << 5) | cz];
            }
        }
    }
    nbr[i] = total > 0 ? 1 : 0;
}

// ---------------------------------------------------------------------------
// Kernel 4: gather, one thread per 4 consecutive z-voxels. Flat grid (max
// TLP, no barriers). Empty-neighborhood threads: 1 byte load + 4 stores.
// Plain (temporal) stores so L2 write-combines the strided dwordx4s.
// ---------------------------------------------------------------------------
__global__ void __launch_bounds__(256)
svox_gather(const float* __restrict__ occ,
            const int* __restrict__ counts,
            const f32x4* __restrict__ lists,
            const unsigned char* __restrict__ nbr,
            f32x4* __restrict__ sem4,
            f32x4* __restrict__ wsum4) {
    int t = blockIdx.x * blockDim.x + threadIdx.x;   // 4,194,304 threads
    int lin0 = t << 2;
    int z0 = lin0 & 255;                             // multiple of 4
    int y  = (lin0 >> 8) & 255;
    int x  = lin0 >> 16;

    float acc[4][4];
#pragma unroll
    for (int q = 0; q < 4; ++q) {
        acc[q][0] = 0.f; acc[q][1] = 0.f; acc[q][2] = 0.f; acc[q][3] = 0.f;
    }

    if (nbr[((x >> 3) << 10) | ((y >> 3) << 5) | (z0 >> 3)]) {
        // cells that can hold a center within windows of voxels z0..z0+3
        int xc0 = max(x - 3, 0) >> 3,  xc1 = min(x + 3, 255) >> 3;
        int yc0 = max(y - 3, 0) >> 3,  yc1 = min(y + 3, 255) >> 3;
        int zc0 = max(z0 - 3, 0) >> 3, zc1 = min(z0 + 6, 255) >> 3;

        int total = 0;
        for (int bx = xc0; bx <= xc1; ++bx)
            for (int by = yc0; by <= yc1; ++by)
                for (int bz = zc0; bz <= zc1; ++bz)
                    total += counts[(bx << 10) | (by << 5) | bz];

        if (total > 0) {
            const float inv = 1.0f / 256.0f;
            float fx  = ((float)x  + 0.5f) * inv - 0.5f;
            float fy  = ((float)y  + 0.5f) * inv - 0.5f;
            float fz0 = ((float)z0 + 0.5f) * inv - 0.5f;

            const f32x4 o4 = __builtin_nontemporal_load((const f32x4*)&occ[lin0]);
            float occv[4] = {o4.x, o4.y, o4.z, o4.w};

            for (int bx = xc0; bx <= xc1; ++bx)
            for (int by = yc0; by <= yc1; ++by)
            for (int bz = zc0; bz <= zc1; ++bz) {
                int cell = (bx << 10) | (by << 5) | bz;
                int cnt = min(counts[cell], CAP);
                int base = cell * CAP;
                for (int j = 0; j < cnt; ++j) {
                    f32x4 r0 = lists[(base + j) * 2 + 0];
                    f32x4 r1 = lists[(base + j) * 2 + 1];
                    int pk = __float_as_int(r0.w);
                    int cxb = (pk >> 20) & 1023;      // cx + 8
                    int cyb = (pk >> 10) & 1023;
                    int czb =  pk        & 1023;
                    unsigned dxi = (unsigned)(x  + 8 - cxb + 3);
                    unsigned dyi = (unsigned)(y  + 8 - cyb + 3);
                    unsigned dzq = (unsigned)(z0 + 8 - czb + 6);
                    if (dxi > 6u || dyi > 6u || dzq > 9u) continue;

                    float dx = fx - r0.x, dy = fy - r0.y;
                    float exy = __expf(-8192.0f * (dx * dx + dy * dy));
                    int czr = czb - 8;
#pragma unroll
                    for (int q = 0; q < 4; ++q) {
                        unsigned dzi = (unsigned)(z0 + q - czr + 3);
                        if (dzi > 6u) continue;
                        if (occv[q] <= 0.0f) continue;
                        float dz = fz0 + (float)q * inv - r0.z;
                        float w = exy * __expf(-8192.0f * dz * dz);
                        acc[q][0] += w * r1.x;
                        acc[q][1] += w * r1.y;
                        acc[q][2] += w * r1.z;
                        acc[q][3] += w;
                    }
                }
            }
        }
    }

    f32x4 s0 = {acc[0][0], acc[0][1], acc[0][2], acc[1][0]};
    f32x4 s1 = {acc[1][1], acc[1][2], acc[2][0], acc[2][1]};
    f32x4 s2 = {acc[2][2], acc[3][0], acc[3][1], acc[3][2]};
    f32x4 sw = {0.001f + acc[0][3], 0.001f + acc[1][3],
                0.001f + acc[2][3], 0.001f + acc[3][3]};
    sem4[t * 3 + 0] = s0;
    sem4[t * 3 + 1] = s1;
    sem4[t * 3 + 2] = s2;
    wsum4[t] = sw;
}

extern "C" void kernel_launch(void* const* d_in, const int* in_sizes, int n_in,
                              void* d_out, int out_size, void* d_ws, size_t ws_size,
                              hipStream_t stream) {
    const float* verts = (const float*)d_in[0];   // (6890,3) f32
    const float* codes = (const float*)d_in[1];   // (6890,3) f32
    const float* occ   = (const float*)d_in[2];   // (256,256,256) f32
    // d_in[3] = smpl_faces (unused by the reference computation)

    f32x4* sem4  = (f32x4*)d_out;                       // 12,582,912 f32x4
    f32x4* wsum4 = (f32x4*)((float*)d_out + SEM_ELEMS); // 4,194,304 f32x4

    int*           counts = (int*)d_ws;                    // 128 KB
    f32x4*         lists  = (f32x4*)(counts + NCELL);      // 16 MB
    unsigned char* nbr    = (unsigned char*)(lists + NCELL * CAP * 2);  // 32 KB

    svox_zero_counts<<<(NCELL + 255) / 256, 256, 0, stream>>>(counts);
    svox_bucket<<<(NV + 255) / 256, 256, 0, stream>>>(verts, codes, counts, lists);
    svox_nbrmask<<<(NCELL + 255) / 256, 256, 0, stream>>>(counts, nbr);
    svox_gather<<<(RES * RES * RES / 4) / 256, 256, 0, stream>>>(
        occ, counts, lists, nbr, sem4, wsum4);
}